// Round 8
// baseline (167.172 us; speedup 1.0000x reference)
//
#include <hip/hip_runtime.h>
#include <hip/hip_bf16.h>

// WaveletBlock fused kernel (f32 in/out): DWT -> GEMM1(+bias,SiLU) -> GEMM2(+bias) -> IDWT
// R11: HBM-granularity attack. Evidence across R3-R10: dur invariant to occupancy/barriers/
// pipelining; hbm_gbps tracks access granularity (256B->1.37, 1KB->1.84 TB/s) -> kernel is
// continuously HBM-busy at pattern-limited ~29% efficiency on 1KB granules @64KB stride.
//  - Tile = 2 DWT rows x 64 pix x 64 ch: 4 h-rows = 2KB contiguous per channel plane.
//  - Each block does 2 ADJACENT tiles; ALL 32 dwordx4 x-loads issued up-front (st0+st1)
//    -> full 4KB span per plane in flight in one burst. Stores: 2KB granules.
//  - 512 threads = 8 waves (4 m-slices x 2 pix-halves); per-wave GEMM identical to the
//    verified R5 shape (acc[4][4]); LDS 67.6KB single buffer, three lives per tile.
//  - XCD-chunked swizzle: each XCD owns 16 contiguous h-rows per plane (8KB spans).
//  - R9 LDS-only barriers (no vmcnt drain): st1 + tile0 stores stay in flight.
// All math verbatim R9/R10 (harness-verified, absmax 0.015625).

typedef __bf16 bf16x8 __attribute__((ext_vector_type(8)));
typedef float  f32x4  __attribute__((ext_vector_type(4)));
typedef unsigned short u16x8 __attribute__((ext_vector_type(8)));

#define SP 264  // LDS row stride in bf16 elems: 528 B == 4 mod 32 banks (dwords);
                // GEMM b128 reads hit the 8-cycle hardware minimum (all 32 banks busy);
                // DWT/IDWT b128 and epilogue b64 are <=2-way.

__device__ __forceinline__ void barrier_lds() {
  // LDS-visibility barrier WITHOUT vmcnt drain (unlike __syncthreads).
  asm volatile("s_waitcnt lgkmcnt(0)\n\ts_barrier" ::: "memory");
}

__device__ __forceinline__ unsigned short f2bf(float f) {
  __hip_bfloat16 h = __float2bfloat16(f);
  return __builtin_bit_cast(unsigned short, h);
}
__device__ __forceinline__ float bf2f(unsigned short s) {
  union { unsigned int i; float f; } v; v.i = ((unsigned int)s) << 16; return v.f;
}
__device__ __forceinline__ float silu(float f) {
  return f / (1.0f + __expf(-f));
}
// Load 8 consecutive f32 weights, convert to a bf16x8 MFMA fragment (fallback path).
__device__ __forceinline__ bf16x8 ldw8(const float* __restrict__ p) {
  const float4 a = *(const float4*)p;
  const float4 b = *(const float4*)(p + 4);
  bf16x8 r;
  r[0] = (__bf16)a.x; r[1] = (__bf16)a.y; r[2] = (__bf16)a.z; r[3] = (__bf16)a.w;
  r[4] = (__bf16)b.x; r[5] = (__bf16)b.y; r[6] = (__bf16)b.z; r[7] = (__bf16)b.w;
  return r;
}

// Prelude: f32 -> bf16 weight conversion into workspace (verbatim R3, no permutation).
__global__ __launch_bounds__(256) void cvt_w(const float* __restrict__ w1,
                                             const float* __restrict__ w2,
                                             unsigned short* __restrict__ o) {
  const int i = (blockIdx.x * 256 + threadIdx.x) * 4;  // grid 64 x 256 covers 65536
  const float4 a = *(const float4*)(w1 + i);
  const float4 b = *(const float4*)(w2 + i);
  *(ushort4*)(o + i)         = make_ushort4(f2bf(a.x), f2bf(a.y), f2bf(a.z), f2bf(a.w));
  *(ushort4*)(o + 65536 + i) = make_ushort4(f2bf(b.x), f2bf(b.y), f2bf(b.z), f2bf(b.w));
}

// Loads for one 2-hh tile: thread (u=t&31, hl=(t>>5)&1, g=t>>6) loads rows 4*hh2+2*hl
// and +1 at cols 4u for planes g*8+i. 16x dwordx4 = 64 VGPRs. Per wave-instr pair:
// 4 rows x 512B = 2KB contiguous per plane; both tiles staged up-front -> 4KB in flight.
__device__ __forceinline__ void load_st(const float* __restrict__ x, int n, int hh2,
                                        int u, int hl, int g, float4 (&st)[16]) {
  const float* xb = x + ((size_t)n * 64 * 128 + (size_t)(4 * hh2 + 2 * hl)) * 128 + 4 * u;
  #pragma unroll
  for (int i = 0; i < 8; ++i) {
    const float* p = xb + (size_t)(g * 8 + i) * (128 * 128);
    st[2 * i]     = *(const float4*)p;          // even h-row, cols 4u..4u+3
    st[2 * i + 1] = *(const float4*)(p + 128);  // odd  h-row, cols 4u..4u+3
  }
}

// Haar DWT of staged regs -> lds[pix][q*64+c], pix = hl*64 + 2u+p (tile row hl, 2 pixels).
__device__ __forceinline__ void dwt_write(const float4 (&st)[16], unsigned short* lds,
                                          int u, int hl, int g) {
  u16x8 v[4][2];
  #pragma unroll
  for (int i = 0; i < 8; ++i) {
    const float4 r0 = st[2 * i];
    const float4 r1 = st[2 * i + 1];
    #pragma unroll
    for (int p = 0; p < 2; ++p) {
      const float x1 = p ? r0.z : r0.x;  // even row, even col
      const float x3 = p ? r0.w : r0.y;  // even row, odd col
      const float x2 = p ? r1.z : r1.x;  // odd row,  even col
      const float x4 = p ? r1.w : r1.y;  // odd row,  odd col
      v[0][p][i] = f2bf(0.5f * ((x1 + x2) + (x3 + x4)));
      v[1][p][i] = f2bf(0.5f * ((x3 + x4) - (x1 + x2)));
      v[2][p][i] = f2bf(0.5f * ((x2 + x4) - (x1 + x3)));
      v[3][p][i] = f2bf(0.5f * ((x1 + x4) - (x2 + x3)));
    }
  }
  #pragma unroll
  for (int p = 0; p < 2; ++p)
    #pragma unroll
    for (int q = 0; q < 4; ++q)
      *(u16x8*)(&lds[(hl * 64 + 2 * u + p) * SP + q * 64 + g * 8]) = v[q][p];
}

// Phases 2-4 for one tile. 8 waves: wave wv = m-slice (wv&3, 64 o/c4 rows) x pix-half
// (wv>>2, 64 pixels). Inner loops identical to R5's verified GEMM; only base offsets new.
template <bool WBF16>
__device__ __forceinline__ void process_tile(unsigned short* lds,
                                             const void* __restrict__ w1p,
                                             const float* __restrict__ b1,
                                             const void* __restrict__ w2p,
                                             const float* __restrict__ b2,
                                             float* __restrict__ out, int n, int hh2,
                                             int t, int u, int hl, int g) {
  const int wv   = t >> 6;        // 0..7
  const int m    = wv & 3;        // o/c4 slice: rows m*64..m*64+63
  const int nb   = wv >> 2;       // pixel half: pix nb*64..nb*64+63
  const int r    = t & 15;        // MFMA row/col-in-tile
  const int quad = (t & 63) >> 4; // MFMA quad: k-offset (inputs) / row-offset (output)

  // ---------------- Phase 2: GEMM1  D[o][pix] = conv_w . x_dwt;  silu -> lds[pix][o] ----------------
  {
    f32x4 acc[4][4];
    #pragma unroll
    for (int mt = 0; mt < 4; ++mt)
      #pragma unroll
      for (int nt = 0; nt < 4; ++nt)
        acc[mt][nt] = (f32x4){0.0f, 0.0f, 0.0f, 0.0f};

    #pragma unroll
    for (int k0 = 0; k0 < 256; k0 += 32) {
      bf16x8 a[4], b[4];
      #pragma unroll
      for (int mt = 0; mt < 4; ++mt) {  // A: conv_w rows o (L2-resident)
        const int row = m * 64 + mt * 16 + r;
        if constexpr (WBF16)
          a[mt] = *(const bf16x8*)((const unsigned short*)w1p + row * 256 + quad * 8 + k0);
        else
          a[mt] = ldw8((const float*)w1p + row * 256 + quad * 8 + k0);
      }
      #pragma unroll
      for (int nt = 0; nt < 4; ++nt)   // B: x_dwt[pix][k] (ds_read_b128)
        b[nt] = *(const bf16x8*)(&lds[(nb * 64 + nt * 16 + r) * SP + quad * 8 + k0]);
      #pragma unroll
      for (int mt = 0; mt < 4; ++mt)
        #pragma unroll
        for (int nt = 0; nt < 4; ++nt)
          acc[mt][nt] = __builtin_amdgcn_mfma_f32_16x16x32_bf16(a[mt], b[nt], acc[mt][nt], 0, 0, 0);
    }
    barrier_lds();  // all GEMM1 LDS reads done (staged loads/stores stay in flight)

    // Epilogue: lane holds 4 consecutive o (rows) at col pix -> b64 LDS write
    #pragma unroll
    for (int mt = 0; mt < 4; ++mt) {
      const int ob = m * 64 + mt * 16 + quad * 4;
      const float4 bb = *(const float4*)(b1 + ob);
      #pragma unroll
      for (int nt = 0; nt < 4; ++nt) {
        const int pix = nb * 64 + nt * 16 + r;
        ushort4 v;
        v.x = f2bf(silu(acc[mt][nt][0] + bb.x));
        v.y = f2bf(silu(acc[mt][nt][1] + bb.y));
        v.z = f2bf(silu(acc[mt][nt][2] + bb.z));
        v.w = f2bf(silu(acc[mt][nt][3] + bb.w));
        *(ushort4*)(&lds[pix * SP + ob]) = v;
      }
    }
  }
  barrier_lds();  // feat visible

  // ---------------- Phase 3: GEMM2  D[c4][pix] = conv_out_w . feat -> lds[pix][c4] ----------------
  {
    f32x4 acc[4][4];
    #pragma unroll
    for (int mt = 0; mt < 4; ++mt)
      #pragma unroll
      for (int nt = 0; nt < 4; ++nt)
        acc[mt][nt] = (f32x4){0.0f, 0.0f, 0.0f, 0.0f};

    #pragma unroll
    for (int k0 = 0; k0 < 256; k0 += 32) {
      bf16x8 a[4], b[4];
      #pragma unroll
      for (int mt = 0; mt < 4; ++mt) {  // A: conv_out_w rows c4
        const int row = m * 64 + mt * 16 + r;
        if constexpr (WBF16)
          a[mt] = *(const bf16x8*)((const unsigned short*)w2p + row * 256 + quad * 8 + k0);
        else
          a[mt] = ldw8((const float*)w2p + row * 256 + quad * 8 + k0);
      }
      #pragma unroll
      for (int nt = 0; nt < 4; ++nt)   // B: feat[pix][o]
        b[nt] = *(const bf16x8*)(&lds[(nb * 64 + nt * 16 + r) * SP + quad * 8 + k0]);
      #pragma unroll
      for (int mt = 0; mt < 4; ++mt)
        #pragma unroll
        for (int nt = 0; nt < 4; ++nt)
          acc[mt][nt] = __builtin_amdgcn_mfma_f32_16x16x32_bf16(a[mt], b[nt], acc[mt][nt], 0, 0, 0);
    }
    barrier_lds();  // all GEMM2 LDS reads done

    #pragma unroll
    for (int mt = 0; mt < 4; ++mt) {
      const int cb = m * 64 + mt * 16 + quad * 4;
      const float4 bb = *(const float4*)(b2 + cb);
      #pragma unroll
      for (int nt = 0; nt < 4; ++nt) {
        const int pix = nb * 64 + nt * 16 + r;
        ushort4 v;
        v.x = f2bf(acc[mt][nt][0] + bb.x);
        v.y = f2bf(acc[mt][nt][1] + bb.y);
        v.z = f2bf(acc[mt][nt][2] + bb.z);
        v.w = f2bf(acc[mt][nt][3] + bb.w);
        *(ushort4*)(&lds[pix * SP + cb]) = v;
      }
    }
  }
  barrier_lds();  // y visible

  // ---------------- Phase 4: IDWT + float4 stores (16B/lane, 2KB/plane granules) ----------------
  {
    float* ob_ = out + ((size_t)n * 64 * 128 + (size_t)(4 * hh2 + 2 * hl)) * 128 + 4 * u;
    u16x8 yq[2][4];
    #pragma unroll
    for (int p = 0; p < 2; ++p)
      #pragma unroll
      for (int q = 0; q < 4; ++q)
        yq[p][q] = *(const u16x8*)(&lds[(hl * 64 + 2 * u + p) * SP + q * 64 + g * 8]);
    #pragma unroll
    for (int i = 0; i < 8; ++i) {
      float4 e, o;  // even/odd h-row, cols 4u..4u+3
      #pragma unroll
      for (int p = 0; p < 2; ++p) {
        const float y1 = 0.5f * bf2f(yq[p][0][i]);
        const float y2 = 0.5f * bf2f(yq[p][1][i]);
        const float y3 = 0.5f * bf2f(yq[p][2][i]);
        const float y4 = 0.5f * bf2f(yq[p][3][i]);
        const float s14 = y1 + y4, s23 = y2 + y3;
        const float d14 = y1 - y4, d23 = y2 - y3;
        if (p == 0) { e.x = s14 - s23; e.y = d14 + d23; o.x = d14 - d23; o.y = s14 + s23; }
        else        { e.z = s14 - s23; e.w = d14 + d23; o.z = d14 - d23; o.w = s14 + s23; }
      }
      float* prow = ob_ + (size_t)(g * 8 + i) * (128 * 128);
      *(float4*)prow         = e;
      *(float4*)(prow + 128) = o;
    }
  }
}

template <bool WBF16>
__global__ __launch_bounds__(512, 2)
void wavelet_fused(const float* __restrict__ x,
                   const void* __restrict__ w1p,
                   const float* __restrict__ b1,
                   const void* __restrict__ w2p,
                   const float* __restrict__ b2,
                   float* __restrict__ out)
{
  // One buffer, three lives per tile: x_dwt [128 pix][c4] -> feat [128 pix][o] -> y.
  __shared__ unsigned short lds[128 * SP];  // 67,584 B

  const int t  = threadIdx.x;
  const int u  = t & 31;          // 4-col group (pixels 2u, 2u+1)
  const int hl = (t >> 5) & 1;    // tile DWT-row (0/1)
  const int g  = t >> 6;          // 8-channel group [0,8)

  // XCD-chunked swizzle (bijective, grid 256 = 8 XCD x 32): XCD owns hh2 in
  // [4*xcd, 4*xcd+4) -> 16 contiguous h-rows (8KB) per channel plane per XCD.
  const int xcd  = blockIdx.x & 7;
  const int j    = blockIdx.x >> 3;       // 0..31
  const int n    = j >> 1;                // image 0..15
  const int hh2a = 4 * xcd + 2 * (j & 1); // first tile; second = hh2a+1 (adjacent)

  float4 st0[16], st1[16];  // 128 staging VGPRs: both tiles' x issued up-front
  load_st(x, n, hh2a,     u, hl, g, st0);
  load_st(x, n, hh2a + 1, u, hl, g, st1);  // full 4KB/plane in flight in one burst

  dwt_write(st0, lds, u, hl, g);
  barrier_lds();                   // x_dwt(tile0) visible; st1 stays in flight

  process_tile<WBF16>(lds, w1p, b1, w2p, b2, out, n, hh2a, t, u, hl, g);

  barrier_lds();                   // phase-4 tile0 LDS reads done before overwrite
  dwt_write(st1, lds, u, hl, g);   // tile1 DWT into freed buffer
  barrier_lds();                   // x_dwt(tile1) visible

  process_tile<WBF16>(lds, w1p, b1, w2p, b2, out, n, hh2a + 1, t, u, hl, g);
}

extern "C" void kernel_launch(void* const* d_in, const int* in_sizes, int n_in,
                              void* d_out, int out_size, void* d_ws, size_t ws_size,
                              hipStream_t stream) {
  (void)in_sizes; (void)n_in; (void)out_size;
  const float* x  = (const float*)d_in[0];
  const float* w1 = (const float*)d_in[1];
  const float* b1 = (const float*)d_in[2];
  const float* w2 = (const float*)d_in[3];
  const float* b2 = (const float*)d_in[4];
  float* o = (float*)d_out;

  if (ws_size >= 2u * 65536u * sizeof(unsigned short)) {
    unsigned short* wb = (unsigned short*)d_ws;
    cvt_w<<<dim3(64), dim3(256), 0, stream>>>(w1, w2, wb);
    wavelet_fused<true><<<dim3(256), dim3(512), 0, stream>>>(
        x, wb, b1, wb + 65536, b2, o);
  } else {
    wavelet_fused<false><<<dim3(256), dim3(512), 0, stream>>>(
        x, w1, b1, w2, b2, o);
  }
}

// Round 9
// 165.097 us; speedup vs baseline: 1.0126x; 1.0126x over previous
//
#include <hip/hip_runtime.h>
#include <hip/hip_bf16.h>

// WaveletBlock fused kernel (f32 in/out): DWT -> GEMM1(+bias,SiLU) -> GEMM2(+bias) -> IDWT
// R12 = R11 with the register cap fixed: __launch_bounds__(512,1) (was (512,2), which
// capped VGPR at 128 vs ~200 demand -> ~30MB scratch traffic, the R6 spill signature;
// FETCH 35->45.6MB, WRITE 66.5->87MB). Grid 256 = 1 block/CU, single generation.
// Structure (verbatim R11, passed absmax 0.015625):
//  - Tile = 2 DWT rows x 64 pix x 64 ch: 4 h-rows = 2KB contiguous per channel plane.
//  - Block does 2 ADJACENT tiles; ALL 32 dwordx4 x-loads issued up-front (st0+st1)
//    -> full 4KB span per plane in flight in one burst (the granularity experiment).
//  - 512 threads = 8 waves (4 m-slices x 2 pix-halves), acc[4][4] per wave.
//  - XCD-chunked swizzle; R9 LDS-only barriers (no vmcnt drain).
// Live ranges: st0 dies at dwt_write(st0) pre-GEMM; live-through-GEMM = st1(64)+acc(64)
// +frags(48)+addr(~25) ~= 200 <= 256 cap -> spill-free expected (verify via FETCH/WRITE).

typedef __bf16 bf16x8 __attribute__((ext_vector_type(8)));
typedef float  f32x4  __attribute__((ext_vector_type(4)));
typedef unsigned short u16x8 __attribute__((ext_vector_type(8)));

#define SP 264  // LDS row stride in bf16 elems: 528 B == 4 mod 32 banks (dwords);
                // GEMM b128 reads hit the 8-cycle hardware minimum (all 32 banks busy);
                // DWT/IDWT b128 and epilogue b64 are <=2-way.

__device__ __forceinline__ void barrier_lds() {
  // LDS-visibility barrier WITHOUT vmcnt drain (unlike __syncthreads).
  asm volatile("s_waitcnt lgkmcnt(0)\n\ts_barrier" ::: "memory");
}

__device__ __forceinline__ unsigned short f2bf(float f) {
  __hip_bfloat16 h = __float2bfloat16(f);
  return __builtin_bit_cast(unsigned short, h);
}
__device__ __forceinline__ float bf2f(unsigned short s) {
  union { unsigned int i; float f; } v; v.i = ((unsigned int)s) << 16; return v.f;
}
__device__ __forceinline__ float silu(float f) {
  return f / (1.0f + __expf(-f));
}
// Load 8 consecutive f32 weights, convert to a bf16x8 MFMA fragment (fallback path).
__device__ __forceinline__ bf16x8 ldw8(const float* __restrict__ p) {
  const float4 a = *(const float4*)p;
  const float4 b = *(const float4*)(p + 4);
  bf16x8 r;
  r[0] = (__bf16)a.x; r[1] = (__bf16)a.y; r[2] = (__bf16)a.z; r[3] = (__bf16)a.w;
  r[4] = (__bf16)b.x; r[5] = (__bf16)b.y; r[6] = (__bf16)b.z; r[7] = (__bf16)b.w;
  return r;
}

// Prelude: f32 -> bf16 weight conversion into workspace (verbatim R3, no permutation).
__global__ __launch_bounds__(256) void cvt_w(const float* __restrict__ w1,
                                             const float* __restrict__ w2,
                                             unsigned short* __restrict__ o) {
  const int i = (blockIdx.x * 256 + threadIdx.x) * 4;  // grid 64 x 256 covers 65536
  const float4 a = *(const float4*)(w1 + i);
  const float4 b = *(const float4*)(w2 + i);
  *(ushort4*)(o + i)         = make_ushort4(f2bf(a.x), f2bf(a.y), f2bf(a.z), f2bf(a.w));
  *(ushort4*)(o + 65536 + i) = make_ushort4(f2bf(b.x), f2bf(b.y), f2bf(b.z), f2bf(b.w));
}

// Loads for one 2-hh tile: thread (u=t&31, hl=(t>>5)&1, g=t>>6) loads rows 4*hh2+2*hl
// and +1 at cols 4u for planes g*8+i. 16x dwordx4 = 64 VGPRs. Per wave-instr pair:
// 4 rows x 512B = 2KB contiguous per plane; both tiles staged up-front -> 4KB in flight.
__device__ __forceinline__ void load_st(const float* __restrict__ x, int n, int hh2,
                                        int u, int hl, int g, float4 (&st)[16]) {
  const float* xb = x + ((size_t)n * 64 * 128 + (size_t)(4 * hh2 + 2 * hl)) * 128 + 4 * u;
  #pragma unroll
  for (int i = 0; i < 8; ++i) {
    const float* p = xb + (size_t)(g * 8 + i) * (128 * 128);
    st[2 * i]     = *(const float4*)p;          // even h-row, cols 4u..4u+3
    st[2 * i + 1] = *(const float4*)(p + 128);  // odd  h-row, cols 4u..4u+3
  }
}

// Haar DWT of staged regs -> lds[pix][q*64+c], pix = hl*64 + 2u+p (tile row hl, 2 pixels).
__device__ __forceinline__ void dwt_write(const float4 (&st)[16], unsigned short* lds,
                                          int u, int hl, int g) {
  u16x8 v[4][2];
  #pragma unroll
  for (int i = 0; i < 8; ++i) {
    const float4 r0 = st[2 * i];
    const float4 r1 = st[2 * i + 1];
    #pragma unroll
    for (int p = 0; p < 2; ++p) {
      const float x1 = p ? r0.z : r0.x;  // even row, even col
      const float x3 = p ? r0.w : r0.y;  // even row, odd col
      const float x2 = p ? r1.z : r1.x;  // odd row,  even col
      const float x4 = p ? r1.w : r1.y;  // odd row,  odd col
      v[0][p][i] = f2bf(0.5f * ((x1 + x2) + (x3 + x4)));
      v[1][p][i] = f2bf(0.5f * ((x3 + x4) - (x1 + x2)));
      v[2][p][i] = f2bf(0.5f * ((x2 + x4) - (x1 + x3)));
      v[3][p][i] = f2bf(0.5f * ((x1 + x4) - (x2 + x3)));
    }
  }
  #pragma unroll
  for (int p = 0; p < 2; ++p)
    #pragma unroll
    for (int q = 0; q < 4; ++q)
      *(u16x8*)(&lds[(hl * 64 + 2 * u + p) * SP + q * 64 + g * 8]) = v[q][p];
}

// Phases 2-4 for one tile. 8 waves: wave wv = m-slice (wv&3, 64 o/c4 rows) x pix-half
// (wv>>2, 64 pixels). Inner loops identical to R5's verified GEMM; only base offsets new.
template <bool WBF16>
__device__ __forceinline__ void process_tile(unsigned short* lds,
                                             const void* __restrict__ w1p,
                                             const float* __restrict__ b1,
                                             const void* __restrict__ w2p,
                                             const float* __restrict__ b2,
                                             float* __restrict__ out, int n, int hh2,
                                             int t, int u, int hl, int g) {
  const int wv   = t >> 6;        // 0..7
  const int m    = wv & 3;        // o/c4 slice: rows m*64..m*64+63
  const int nb   = wv >> 2;       // pixel half: pix nb*64..nb*64+63
  const int r    = t & 15;        // MFMA row/col-in-tile
  const int quad = (t & 63) >> 4; // MFMA quad: k-offset (inputs) / row-offset (output)

  // ---------------- Phase 2: GEMM1  D[o][pix] = conv_w . x_dwt;  silu -> lds[pix][o] ----------------
  {
    f32x4 acc[4][4];
    #pragma unroll
    for (int mt = 0; mt < 4; ++mt)
      #pragma unroll
      for (int nt = 0; nt < 4; ++nt)
        acc[mt][nt] = (f32x4){0.0f, 0.0f, 0.0f, 0.0f};

    #pragma unroll
    for (int k0 = 0; k0 < 256; k0 += 32) {
      bf16x8 a[4], b[4];
      #pragma unroll
      for (int mt = 0; mt < 4; ++mt) {  // A: conv_w rows o (L2-resident)
        const int row = m * 64 + mt * 16 + r;
        if constexpr (WBF16)
          a[mt] = *(const bf16x8*)((const unsigned short*)w1p + row * 256 + quad * 8 + k0);
        else
          a[mt] = ldw8((const float*)w1p + row * 256 + quad * 8 + k0);
      }
      #pragma unroll
      for (int nt = 0; nt < 4; ++nt)   // B: x_dwt[pix][k] (ds_read_b128)
        b[nt] = *(const bf16x8*)(&lds[(nb * 64 + nt * 16 + r) * SP + quad * 8 + k0]);
      #pragma unroll
      for (int mt = 0; mt < 4; ++mt)
        #pragma unroll
        for (int nt = 0; nt < 4; ++nt)
          acc[mt][nt] = __builtin_amdgcn_mfma_f32_16x16x32_bf16(a[mt], b[nt], acc[mt][nt], 0, 0, 0);
    }
    barrier_lds();  // all GEMM1 LDS reads done (staged loads/stores stay in flight)

    // Epilogue: lane holds 4 consecutive o (rows) at col pix -> b64 LDS write
    #pragma unroll
    for (int mt = 0; mt < 4; ++mt) {
      const int ob = m * 64 + mt * 16 + quad * 4;
      const float4 bb = *(const float4*)(b1 + ob);
      #pragma unroll
      for (int nt = 0; nt < 4; ++nt) {
        const int pix = nb * 64 + nt * 16 + r;
        ushort4 v;
        v.x = f2bf(silu(acc[mt][nt][0] + bb.x));
        v.y = f2bf(silu(acc[mt][nt][1] + bb.y));
        v.z = f2bf(silu(acc[mt][nt][2] + bb.z));
        v.w = f2bf(silu(acc[mt][nt][3] + bb.w));
        *(ushort4*)(&lds[pix * SP + ob]) = v;
      }
    }
  }
  barrier_lds();  // feat visible

  // ---------------- Phase 3: GEMM2  D[c4][pix] = conv_out_w . feat -> lds[pix][c4] ----------------
  {
    f32x4 acc[4][4];
    #pragma unroll
    for (int mt = 0; mt < 4; ++mt)
      #pragma unroll
      for (int nt = 0; nt < 4; ++nt)
        acc[mt][nt] = (f32x4){0.0f, 0.0f, 0.0f, 0.0f};

    #pragma unroll
    for (int k0 = 0; k0 < 256; k0 += 32) {
      bf16x8 a[4], b[4];
      #pragma unroll
      for (int mt = 0; mt < 4; ++mt) {  // A: conv_out_w rows c4
        const int row = m * 64 + mt * 16 + r;
        if constexpr (WBF16)
          a[mt] = *(const bf16x8*)((const unsigned short*)w2p + row * 256 + quad * 8 + k0);
        else
          a[mt] = ldw8((const float*)w2p + row * 256 + quad * 8 + k0);
      }
      #pragma unroll
      for (int nt = 0; nt < 4; ++nt)   // B: feat[pix][o]
        b[nt] = *(const bf16x8*)(&lds[(nb * 64 + nt * 16 + r) * SP + quad * 8 + k0]);
      #pragma unroll
      for (int mt = 0; mt < 4; ++mt)
        #pragma unroll
        for (int nt = 0; nt < 4; ++nt)
          acc[mt][nt] = __builtin_amdgcn_mfma_f32_16x16x32_bf16(a[mt], b[nt], acc[mt][nt], 0, 0, 0);
    }
    barrier_lds();  // all GEMM2 LDS reads done

    #pragma unroll
    for (int mt = 0; mt < 4; ++mt) {
      const int cb = m * 64 + mt * 16 + quad * 4;
      const float4 bb = *(const float4*)(b2 + cb);
      #pragma unroll
      for (int nt = 0; nt < 4; ++nt) {
        const int pix = nb * 64 + nt * 16 + r;
        ushort4 v;
        v.x = f2bf(acc[mt][nt][0] + bb.x);
        v.y = f2bf(acc[mt][nt][1] + bb.y);
        v.z = f2bf(acc[mt][nt][2] + bb.z);
        v.w = f2bf(acc[mt][nt][3] + bb.w);
        *(ushort4*)(&lds[pix * SP + cb]) = v;
      }
    }
  }
  barrier_lds();  // y visible

  // ---------------- Phase 4: IDWT + float4 stores (16B/lane, 2KB/plane granules) ----------------
  {
    float* ob_ = out + ((size_t)n * 64 * 128 + (size_t)(4 * hh2 + 2 * hl)) * 128 + 4 * u;
    u16x8 yq[2][4];
    #pragma unroll
    for (int p = 0; p < 2; ++p)
      #pragma unroll
      for (int q = 0; q < 4; ++q)
        yq[p][q] = *(const u16x8*)(&lds[(hl * 64 + 2 * u + p) * SP + q * 64 + g * 8]);
    #pragma unroll
    for (int i = 0; i < 8; ++i) {
      float4 e, o;  // even/odd h-row, cols 4u..4u+3
      #pragma unroll
      for (int p = 0; p < 2; ++p) {
        const float y1 = 0.5f * bf2f(yq[p][0][i]);
        const float y2 = 0.5f * bf2f(yq[p][1][i]);
        const float y3 = 0.5f * bf2f(yq[p][2][i]);
        const float y4 = 0.5f * bf2f(yq[p][3][i]);
        const float s14 = y1 + y4, s23 = y2 + y3;
        const float d14 = y1 - y4, d23 = y2 - y3;
        if (p == 0) { e.x = s14 - s23; e.y = d14 + d23; o.x = d14 - d23; o.y = s14 + s23; }
        else        { e.z = s14 - s23; e.w = d14 + d23; o.z = d14 - d23; o.w = s14 + s23; }
      }
      float* prow = ob_ + (size_t)(g * 8 + i) * (128 * 128);
      *(float4*)prow         = e;
      *(float4*)(prow + 128) = o;
    }
  }
}

template <bool WBF16>
__global__ __launch_bounds__(512, 1)
void wavelet_fused(const float* __restrict__ x,
                   const void* __restrict__ w1p,
                   const float* __restrict__ b1,
                   const void* __restrict__ w2p,
                   const float* __restrict__ b2,
                   float* __restrict__ out)
{
  // One buffer, three lives per tile: x_dwt [128 pix][c4] -> feat [128 pix][o] -> y.
  __shared__ unsigned short lds[128 * SP];  // 67,584 B

  const int t  = threadIdx.x;
  const int u  = t & 31;          // 4-col group (pixels 2u, 2u+1)
  const int hl = (t >> 5) & 1;    // tile DWT-row (0/1)
  const int g  = t >> 6;          // 8-channel group [0,8)

  // XCD-chunked swizzle (bijective, grid 256 = 8 XCD x 32): XCD owns hh2 in
  // [4*xcd, 4*xcd+4) -> 16 contiguous h-rows (8KB) per channel plane per XCD.
  const int xcd  = blockIdx.x & 7;
  const int j    = blockIdx.x >> 3;       // 0..31
  const int n    = j >> 1;                // image 0..15
  const int hh2a = 4 * xcd + 2 * (j & 1); // first tile; second = hh2a+1 (adjacent)

  float4 st0[16], st1[16];  // 128 staging VGPRs: both tiles' x issued up-front
  load_st(x, n, hh2a,     u, hl, g, st0);
  load_st(x, n, hh2a + 1, u, hl, g, st1);  // full 4KB/plane in flight in one burst

  dwt_write(st0, lds, u, hl, g);
  barrier_lds();                   // x_dwt(tile0) visible; st1 stays in flight

  process_tile<WBF16>(lds, w1p, b1, w2p, b2, out, n, hh2a, t, u, hl, g);

  barrier_lds();                   // phase-4 tile0 LDS reads done before overwrite
  dwt_write(st1, lds, u, hl, g);   // tile1 DWT into freed buffer
  barrier_lds();                   // x_dwt(tile1) visible

  process_tile<WBF16>(lds, w1p, b1, w2p, b2, out, n, hh2a + 1, t, u, hl, g);
}

extern "C" void kernel_launch(void* const* d_in, const int* in_sizes, int n_in,
                              void* d_out, int out_size, void* d_ws, size_t ws_size,
                              hipStream_t stream) {
  (void)in_sizes; (void)n_in; (void)out_size;
  const float* x  = (const float*)d_in[0];
  const float* w1 = (const float*)d_in[1];
  const float* b1 = (const float*)d_in[2];
  const float* w2 = (const float*)d_in[3];
  const float* b2 = (const float*)d_in[4];
  float* o = (float*)d_out;

  if (ws_size >= 2u * 65536u * sizeof(unsigned short)) {
    unsigned short* wb = (unsigned short*)d_ws;
    cvt_w<<<dim3(64), dim3(256), 0, stream>>>(w1, w2, wb);
    wavelet_fused<true><<<dim3(256), dim3(512), 0, stream>>>(
        x, wb, b1, wb + 65536, b2, o);
  } else {
    wavelet_fused<false><<<dim3(256), dim3(512), 0, stream>>>(
        x, w1, b1, w2, b2, o);
  }
}

// Round 11
// 164.639 us; speedup vs baseline: 1.0154x; 1.0028x over previous
//
#include <hip/hip_runtime.h>
#include <hip/hip_bf16.h>

// WaveletBlock fused kernel (f32 in/out): DWT -> GEMM1(+bias,SiLU) -> GEMM2(+bias) -> IDWT
// R14 = R13 frame with race-surface and queue-discipline fixes:
//  - NO counted vmcnt anywhere (R13's vmcnt(16) boundary raced on replay despite provable
//    arithmetic -- m152 lesson). Boundary = lgkmcnt(0)+s_barrier (R9/R10-proven primitive).
//    rawbuf validity at next phase-1 follows from the IN-ORDER vmem queue: GEMM2's weight
//    waits (issued after the prefetch burst) force prefetch retirement.
//  - Prefetch = ONE 16-slot global_load_lds burst after GEMM1's k-loop (R13's per-k-step
//    trickle stalled ~700cy/k-step: weight-wait at step j drains the step j-1 prefetch
//    mid-flight). A compiler fence keeps w2 loads from hoisting above the burst.
//  - Biases preloaded to registers per block -> no load-waits between burst and GEMM2.
//  - Stores fly across row boundaries (never drained; disjoint addresses).
// Math (DWT/GEMM/epilogues/IDWT), pf_slot layout, XCD mapping: verbatim R13 (first-run-
// correct) / R10 (fully verified).

typedef __bf16 bf16x8 __attribute__((ext_vector_type(8)));
typedef float  f32x4  __attribute__((ext_vector_type(4)));
typedef unsigned short u16x8 __attribute__((ext_vector_type(8)));

#define SP 264  // workbuf row stride in bf16 elems: 528 B == 4 mod 32 banks (dwords);
                // rows 16B-aligned for b128; GEMM-phase accesses <=2-way.

__device__ __forceinline__ void barrier_lds() {
  // LDS-visibility barrier WITHOUT vmcnt drain (unlike __syncthreads).
  asm volatile("s_waitcnt lgkmcnt(0)\n\ts_barrier" ::: "memory");
}

__device__ __forceinline__ unsigned short f2bf(float f) {
  __hip_bfloat16 h = __float2bfloat16(f);
  return __builtin_bit_cast(unsigned short, h);
}
__device__ __forceinline__ float bf2f(unsigned short s) {
  union { unsigned int i; float f; } v; v.i = ((unsigned int)s) << 16; return v.f;
}
__device__ __forceinline__ float silu(float f) {
  return f / (1.0f + __expf(-f));
}
// Load 8 consecutive f32 weights, convert to a bf16x8 MFMA fragment (fallback path).
__device__ __forceinline__ bf16x8 ldw8(const float* __restrict__ p) {
  const float4 a = *(const float4*)p;
  const float4 b = *(const float4*)(p + 4);
  bf16x8 r;
  r[0] = (__bf16)a.x; r[1] = (__bf16)a.y; r[2] = (__bf16)a.z; r[3] = (__bf16)a.w;
  r[4] = (__bf16)b.x; r[5] = (__bf16)b.y; r[6] = (__bf16)b.z; r[7] = (__bf16)b.w;
  return r;
}

// Prelude: f32 -> bf16 weight conversion into workspace (verbatim R3, no permutation).
__global__ __launch_bounds__(256) void cvt_w(const float* __restrict__ w1,
                                             const float* __restrict__ w2,
                                             unsigned short* __restrict__ o) {
  const int i = (blockIdx.x * 256 + threadIdx.x) * 4;  // grid 64 x 256 covers 65536
  const float4 a = *(const float4*)(w1 + i);
  const float4 b = *(const float4*)(w2 + i);
  *(ushort4*)(o + i)         = make_ushort4(f2bf(a.x), f2bf(a.y), f2bf(a.z), f2bf(a.w));
  *(ushort4*)(o + 65536 + i) = make_ushort4(f2bf(b.x), f2bf(b.y), f2bf(b.z), f2bf(b.w));
}

// One prefetch slot: global_load_lds 16B/lane of x row (2hh + s&1), plane g*8 + s>>1,
// cols 4u..4u+3 -> rawbuf slot s at (s*256 + t)*16 bytes (wave-uniform base + lane*16).
__device__ __forceinline__ void pf_slot(const float* __restrict__ x, int n, int hh,
                                        int u, int g, int t, int s,
                                        unsigned char* rawb) {
  const int plane = g * 8 + (s >> 1);
  const float* gp = x + ((size_t)(n * 64 + plane) * 128
                       + (size_t)(2 * hh + (s & 1))) * 128 + 4 * u;
  unsigned char* lp = rawb + ((size_t)s * 256 + (t & 192)) * 16;  // wave-uniform base
  __builtin_amdgcn_global_load_lds(
      (const __attribute__((address_space(1))) unsigned int*)gp,
      (__attribute__((address_space(3))) unsigned int*)lp, 16, 0, 0);
}

template <bool WBF16>
__global__ __launch_bounds__(256, 1)
void wavelet_fused(const float* __restrict__ x,
                   const void* __restrict__ w1p,
                   const float* __restrict__ b1,
                   const void* __restrict__ w2p,
                   const float* __restrict__ b2,
                   float* __restrict__ out)
{
  // rawbuf: 16 slots x 256 threads x 16B = 64KB raw f32 x (wave-private stripes).
  // workbuf: three lives per row: x_dwt [pix][c4] -> feat [pix][o] -> y [pix][c4].
  __shared__ __align__(16) unsigned char smem[65536 + 64 * SP * 2];  // 99,328 B
  unsigned char*  rawb = smem;
  unsigned short* work = (unsigned short*)(smem + 65536);

  const int t  = threadIdx.x;
  const int u  = t & 31;          // 4-col group (pixels 2u, 2u+1) for DWT/IDWT
  const int g  = t >> 5;          // 8-channel group [0,8)
  const int wv   = t >> 6;        // wave id: o/c4 m-slice of 64 rows (GEMM)
  const int r    = t & 15;        // MFMA row/col-in-tile
  const int quad = (t & 63) >> 4; // MFMA quad

  // XCD-chunked mapping (grid 256 = 8 XCD x 32): XCD owns hh in [8*xcd, 8*xcd+8) per
  // image; each block gets 4 CONSECUTIVE hh -> 8 h-rows = 4KB contiguous per plane.
  const int b   = blockIdx.x;
  const int n   = b >> 4;                                // image 0..15
  const int hhb = (b & 7) * 8 + ((b >> 3) & 1) * 4;      // first DWT row of 4

  // Biases preloaded once per block (32 VGPR) -> no global load-waits inside the row loop
  // other than weight loads (keeps the prefetch-drain point unique: GEMM2's first wait).
  float4 bb1[4], bb2[4];
  #pragma unroll
  for (int mt = 0; mt < 4; ++mt) {
    bb1[mt] = *(const float4*)(b1 + wv * 64 + mt * 16 + quad * 4);
    bb2[mt] = *(const float4*)(b2 + wv * 64 + mt * 16 + quad * 4);
  }

  // ---- prologue: stage row hhb into rawbuf (no VGPR staging) ----
  #pragma unroll
  for (int s = 0; s < 16; ++s) pf_slot(x, n, hhb, u, g, t, s, rawb);
  asm volatile("s_waitcnt vmcnt(0)" ::: "memory");  // rawbuf(row0) landed (wave-private)

  for (int i = 0; i < 4; ++i) {
    const int hh = hhb + i;

    // ---------------- Phase 1: DWT rawbuf -> work[pix][q*64+c] (math verbatim R10) ----
    {
      u16x8 v[4][2];
      #pragma unroll
      for (int ii = 0; ii < 8; ++ii) {
        const float4 r0 = *(const float4*)(rawb + ((size_t)(2 * ii) * 256 + t) * 16);
        const float4 r1 = *(const float4*)(rawb + ((size_t)(2 * ii + 1) * 256 + t) * 16);
        #pragma unroll
        for (int p = 0; p < 2; ++p) {
          const float x1 = p ? r0.z : r0.x;  // even row, even col
          const float x3 = p ? r0.w : r0.y;  // even row, odd col
          const float x2 = p ? r1.z : r1.x;  // odd row,  even col
          const float x4 = p ? r1.w : r1.y;  // odd row,  odd col
          v[0][p][ii] = f2bf(0.5f * ((x1 + x2) + (x3 + x4)));
          v[1][p][ii] = f2bf(0.5f * ((x3 + x4) - (x1 + x2)));
          v[2][p][ii] = f2bf(0.5f * ((x2 + x4) - (x1 + x3)));
          v[3][p][ii] = f2bf(0.5f * ((x1 + x4) - (x2 + x3)));
        }
      }
      #pragma unroll
      for (int p = 0; p < 2; ++p)
        #pragma unroll
        for (int q = 0; q < 4; ++q)
          *(u16x8*)(&work[(2 * u + p) * SP + q * 64 + g * 8]) = v[q][p];
    }
    barrier_lds();  // x_dwt visible; this wave's rawbuf ds_reads drained (lgkm)

    // ---------------- Phase 2: GEMM1 (clean k-loop) ----------------
    f32x4 acc[4][4];
    #pragma unroll
    for (int mt = 0; mt < 4; ++mt)
      #pragma unroll
      for (int nt = 0; nt < 4; ++nt)
        acc[mt][nt] = (f32x4){0.0f, 0.0f, 0.0f, 0.0f};

    #pragma unroll
    for (int k0 = 0; k0 < 256; k0 += 32) {
      bf16x8 a[4], bfr[4];
      #pragma unroll
      for (int mt = 0; mt < 4; ++mt) {  // A: conv_w rows o (L2-resident)
        const int row = wv * 64 + mt * 16 + r;
        if constexpr (WBF16)
          a[mt] = *(const bf16x8*)((const unsigned short*)w1p + row * 256 + quad * 8 + k0);
        else
          a[mt] = ldw8((const float*)w1p + row * 256 + quad * 8 + k0);
      }
      #pragma unroll
      for (int nt = 0; nt < 4; ++nt)   // B: x_dwt[pix][k] (ds_read_b128)
        bfr[nt] = *(const bf16x8*)(&work[(nt * 16 + r) * SP + quad * 8 + k0]);
      #pragma unroll
      for (int mt = 0; mt < 4; ++mt)
        #pragma unroll
        for (int nt = 0; nt < 4; ++nt)
          acc[mt][nt] = __builtin_amdgcn_mfma_f32_16x16x32_bf16(a[mt], bfr[nt], acc[mt][nt], 0, 0, 0);
    }

    // ---- prefetch burst for row i+1: issued ONCE, after all GEMM1 weight loads.
    // In-flight window = epilogue + barrier; GEMM2's first weight-wait (in-order queue)
    // is the unique drain point. Fence keeps w2 loads from hoisting above the burst.
    if (i < 3) {
      #pragma unroll
      for (int s = 0; s < 16; ++s) pf_slot(x, n, hh + 1, u, g, t, s, rawb);
      asm volatile("" ::: "memory");
    }

    barrier_lds();  // all GEMM1 LDS reads done; epilogue may overwrite work

    #pragma unroll
    for (int mt = 0; mt < 4; ++mt) {   // epilogue: bias+SiLU -> work[pix][o]
      const int ob = wv * 64 + mt * 16 + quad * 4;
      #pragma unroll
      for (int nt = 0; nt < 4; ++nt) {
        const int pix = nt * 16 + r;
        ushort4 v;
        v.x = f2bf(silu(acc[mt][nt][0] + bb1[mt].x));
        v.y = f2bf(silu(acc[mt][nt][1] + bb1[mt].y));
        v.z = f2bf(silu(acc[mt][nt][2] + bb1[mt].z));
        v.w = f2bf(silu(acc[mt][nt][3] + bb1[mt].w));
        *(ushort4*)(&work[pix * SP + ob]) = v;
      }
    }
    barrier_lds();  // feat visible

    // ---------------- Phase 3: GEMM2 (weight waits drain the prefetch burst once) ----
    #pragma unroll
    for (int mt = 0; mt < 4; ++mt)
      #pragma unroll
      for (int nt = 0; nt < 4; ++nt)
        acc[mt][nt] = (f32x4){0.0f, 0.0f, 0.0f, 0.0f};

    #pragma unroll
    for (int k0 = 0; k0 < 256; k0 += 32) {
      bf16x8 a[4], bfr[4];
      #pragma unroll
      for (int mt = 0; mt < 4; ++mt) {  // A: conv_out_w rows c4
        const int row = wv * 64 + mt * 16 + r;
        if constexpr (WBF16)
          a[mt] = *(const bf16x8*)((const unsigned short*)w2p + row * 256 + quad * 8 + k0);
        else
          a[mt] = ldw8((const float*)w2p + row * 256 + quad * 8 + k0);
      }
      #pragma unroll
      for (int nt = 0; nt < 4; ++nt)   // B: feat[pix][o]
        bfr[nt] = *(const bf16x8*)(&work[(nt * 16 + r) * SP + quad * 8 + k0]);
      #pragma unroll
      for (int mt = 0; mt < 4; ++mt)
        #pragma unroll
        for (int nt = 0; nt < 4; ++nt)
          acc[mt][nt] = __builtin_amdgcn_mfma_f32_16x16x32_bf16(a[mt], bfr[nt], acc[mt][nt], 0, 0, 0);
    }
    barrier_lds();  // all GEMM2 LDS reads done

    #pragma unroll
    for (int mt = 0; mt < 4; ++mt) {   // epilogue: bias -> work[pix][c4]
      const int cb = wv * 64 + mt * 16 + quad * 4;
      #pragma unroll
      for (int nt = 0; nt < 4; ++nt) {
        const int pix = nt * 16 + r;
        ushort4 v;
        v.x = f2bf(acc[mt][nt][0] + bb2[mt].x);
        v.y = f2bf(acc[mt][nt][1] + bb2[mt].y);
        v.z = f2bf(acc[mt][nt][2] + bb2[mt].z);
        v.w = f2bf(acc[mt][nt][3] + bb2[mt].w);
        *(ushort4*)(&work[pix * SP + cb]) = v;
      }
    }
    barrier_lds();  // y visible

    // ---------------- Phase 4: IDWT + float4 stores (verbatim R10; stores fly) --------
    {
      float* ob_ = out + ((size_t)n * 64 * 128 + (size_t)(2 * hh)) * 128 + 4 * u;
      u16x8 yq[2][4];
      #pragma unroll
      for (int p = 0; p < 2; ++p)
        #pragma unroll
        for (int q = 0; q < 4; ++q)
          yq[p][q] = *(const u16x8*)(&work[(2 * u + p) * SP + q * 64 + g * 8]);
      #pragma unroll
      for (int ii = 0; ii < 8; ++ii) {
        float4 e, o;  // even/odd h-row, cols 4u..4u+3
        #pragma unroll
        for (int p = 0; p < 2; ++p) {
          const float y1 = 0.5f * bf2f(yq[p][0][ii]);
          const float y2 = 0.5f * bf2f(yq[p][1][ii]);
          const float y3 = 0.5f * bf2f(yq[p][2][ii]);
          const float y4 = 0.5f * bf2f(yq[p][3][ii]);
          const float s14 = y1 + y4, s23 = y2 + y3;
          const float d14 = y1 - y4, d23 = y2 - y3;
          if (p == 0) { e.x = s14 - s23; e.y = d14 + d23; o.x = d14 - d23; o.y = s14 + s23; }
          else        { e.z = s14 - s23; e.w = d14 + d23; o.z = d14 - d23; o.w = s14 + s23; }
        }
        float* prow = ob_ + (size_t)(g * 8 + ii) * (128 * 128);
        *(float4*)prow         = e;
        *(float4*)(prow + 128) = o;
      }
    }

    // Row boundary: LDS-only barrier (R9/R10-proven). Stores stay in flight (disjoint
    // addresses). rawbuf(row i+1) already landed: its prefetches retired before GEMM2's
    // weight data was usable (in-order vmem queue).
    barrier_lds();
  }
}

extern "C" void kernel_launch(void* const* d_in, const int* in_sizes, int n_in,
                              void* d_out, int out_size, void* d_ws, size_t ws_size,
                              hipStream_t stream) {
  (void)in_sizes; (void)n_in; (void)out_size;
  const float* x  = (const float*)d_in[0];
  const float* w1 = (const float*)d_in[1];
  const float* b1 = (const float*)d_in[2];
  const float* w2 = (const float*)d_in[3];
  const float* b2 = (const float*)d_in[4];
  float* o = (float*)d_out;

  if (ws_size >= 2u * 65536u * sizeof(unsigned short)) {
    unsigned short* wb = (unsigned short*)d_ws;
    cvt_w<<<dim3(64), dim3(256), 0, stream>>>(w1, w2, wb);
    wavelet_fused<true><<<dim3(256), dim3(256), 0, stream>>>(
        x, wb, b1, wb + 65536, b2, o);
  } else {
    wavelet_fused<false><<<dim3(256), dim3(256), 0, stream>>>(
        x, w1, b1, w2, b2, o);
  }
}

// Round 12
// 151.246 us; speedup vs baseline: 1.1053x; 1.0886x over previous
//
#include <hip/hip_runtime.h>
#include <hip/hip_bf16.h>

// WaveletBlock fused kernel (f32 in/out): DWT -> GEMM1(+bias,SiLU) -> GEMM2(+bias) -> IDWT
// R15 = R10's verified math/pattern at 4 blocks/CU (cross-block overlap, the only
// latency-hiding mechanism that works against the per-wave in-order vmcnt queue --
// R5/R9/R13 all showed intra-wave prefetch is drained by the next load-wait).
//  - grid 1024, ONE row per block (intra-wave 2-row pipeline removed: it was placebo).
//  - float4 16B/lane loads/stores + XCD-chunked swizzle (R10's +7%, kept verbatim).
//  - LDS 33.8KB -> 4 blocks/CU (135KB/160KB); VGPR <=128 -> 16 waves/CU resident.
//  - R9 LDS-only barriers (no vmcnt drain) so stores fly across phase boundaries.
// All arithmetic (load/DWT/GEMM/epilogues/IDWT) verbatim R10 (harness-verified 0.015625).

typedef __bf16 bf16x8 __attribute__((ext_vector_type(8)));
typedef float  f32x4  __attribute__((ext_vector_type(4)));
typedef unsigned short u16x8 __attribute__((ext_vector_type(8)));

#define SP 264  // LDS row stride in bf16 elems: 528 B == 4 mod 32 banks (dwords);
                // rows 16B-aligned for ds_read_b128. GEMM-phase accesses <=2-way;
                // phase-1/4 b128 accesses alias 8-way = the 8-cycle hardware minimum.

__device__ __forceinline__ void barrier_lds() {
  // LDS-visibility barrier WITHOUT vmcnt drain (unlike __syncthreads).
  asm volatile("s_waitcnt lgkmcnt(0)\n\ts_barrier" ::: "memory");
}

__device__ __forceinline__ unsigned short f2bf(float f) {
  __hip_bfloat16 h = __float2bfloat16(f);
  return __builtin_bit_cast(unsigned short, h);
}
__device__ __forceinline__ float bf2f(unsigned short s) {
  union { unsigned int i; float f; } v; v.i = ((unsigned int)s) << 16; return v.f;
}
__device__ __forceinline__ float silu(float f) {
  return f / (1.0f + __expf(-f));
}
// Load 8 consecutive f32 weights, convert to a bf16x8 MFMA fragment (fallback path).
__device__ __forceinline__ bf16x8 ldw8(const float* __restrict__ p) {
  const float4 a = *(const float4*)p;
  const float4 b = *(const float4*)(p + 4);
  bf16x8 r;
  r[0] = (__bf16)a.x; r[1] = (__bf16)a.y; r[2] = (__bf16)a.z; r[3] = (__bf16)a.w;
  r[4] = (__bf16)b.x; r[5] = (__bf16)b.y; r[6] = (__bf16)b.z; r[7] = (__bf16)b.w;
  return r;
}

// Prelude: f32 -> bf16 weight conversion into workspace (verbatim R3, no permutation).
__global__ __launch_bounds__(256) void cvt_w(const float* __restrict__ w1,
                                             const float* __restrict__ w2,
                                             unsigned short* __restrict__ o) {
  const int i = (blockIdx.x * 256 + threadIdx.x) * 4;  // grid 64 x 256 covers 65536
  const float4 a = *(const float4*)(w1 + i);
  const float4 b = *(const float4*)(w2 + i);
  *(ushort4*)(o + i)         = make_ushort4(f2bf(a.x), f2bf(a.y), f2bf(a.z), f2bf(a.w));
  *(ushort4*)(o + 65536 + i) = make_ushort4(f2bf(b.x), f2bf(b.y), f2bf(b.z), f2bf(b.w));
}

// Phase-1a: one row's x loads as float4 (16B/lane): thread t (u=t&31, g=t>>5) loads
// cols 4u..4u+3 of rows 2hh/2hh+1 for planes g*8..g*8+7. 16x dwordx4 = 64 VGPRs.
__device__ __forceinline__ void load_st(const float* __restrict__ x, int n, int hh,
                                        int u, int g, float4 (&st)[16]) {
  const float* xb = x + ((size_t)n * 64 * 128 + (size_t)(2 * hh)) * 128 + 4 * u;
  #pragma unroll
  for (int i = 0; i < 8; ++i) {
    const float* p = xb + (size_t)(g * 8 + i) * (128 * 128);
    st[2 * i]     = *(const float4*)p;          // row 2hh,   cols 4u..4u+3
    st[2 * i + 1] = *(const float4*)(p + 128);  // row 2hh+1, cols 4u..4u+3
  }
}

// Phase-1b: Haar DWT of staged regs -> lds[pix][q*64+c] as bf16, pixels 2u and 2u+1.
__device__ __forceinline__ void dwt_write(const float4 (&st)[16], unsigned short* lds,
                                          int u, int g) {
  u16x8 v[4][2];
  #pragma unroll
  for (int i = 0; i < 8; ++i) {
    const float4 r0 = st[2 * i];
    const float4 r1 = st[2 * i + 1];
    #pragma unroll
    for (int p = 0; p < 2; ++p) {
      const float x1 = p ? r0.z : r0.x;  // even row, even col
      const float x3 = p ? r0.w : r0.y;  // even row, odd col
      const float x2 = p ? r1.z : r1.x;  // odd row,  even col
      const float x4 = p ? r1.w : r1.y;  // odd row,  odd col
      v[0][p][i] = f2bf(0.5f * ((x1 + x2) + (x3 + x4)));
      v[1][p][i] = f2bf(0.5f * ((x3 + x4) - (x1 + x2)));
      v[2][p][i] = f2bf(0.5f * ((x2 + x4) - (x1 + x3)));
      v[3][p][i] = f2bf(0.5f * ((x1 + x4) - (x2 + x3)));
    }
  }
  #pragma unroll
  for (int p = 0; p < 2; ++p)
    #pragma unroll
    for (int q = 0; q < 4; ++q)
      *(u16x8*)(&lds[(2 * u + p) * SP + q * 64 + g * 8]) = v[q][p];
}

// Phases 2-4 for one row (verbatim R10).
template <bool WBF16>
__device__ __forceinline__ void process_row(unsigned short* lds,
                                            const void* __restrict__ w1p,
                                            const float* __restrict__ b1,
                                            const void* __restrict__ w2p,
                                            const float* __restrict__ b2,
                                            float* __restrict__ out, int n, int hh,
                                            int t, int u, int g) {
  const int wv   = t >> 6;        // wave id: o-slice / c4-slice of 64 rows
  const int r    = t & 15;        // MFMA row/col-in-tile
  const int quad = (t & 63) >> 4; // MFMA quad: k-offset (inputs) / row-offset (output)

  // ---------------- Phase 2: GEMM1  D[o][pix] = conv_w . x_dwt;  silu -> lds[pix][o] ----------------
  {
    f32x4 acc[4][4];
    #pragma unroll
    for (int mt = 0; mt < 4; ++mt)
      #pragma unroll
      for (int nt = 0; nt < 4; ++nt)
        acc[mt][nt] = (f32x4){0.0f, 0.0f, 0.0f, 0.0f};

    #pragma unroll
    for (int k0 = 0; k0 < 256; k0 += 32) {
      bf16x8 a[4], b[4];
      #pragma unroll
      for (int mt = 0; mt < 4; ++mt) {  // A: conv_w rows o (L2-resident)
        const int row = wv * 64 + mt * 16 + r;
        if constexpr (WBF16)
          a[mt] = *(const bf16x8*)((const unsigned short*)w1p + row * 256 + quad * 8 + k0);
        else
          a[mt] = ldw8((const float*)w1p + row * 256 + quad * 8 + k0);
      }
      #pragma unroll
      for (int nt = 0; nt < 4; ++nt)   // B: x_dwt[pix][k] (ds_read_b128)
        b[nt] = *(const bf16x8*)(&lds[(nt * 16 + r) * SP + quad * 8 + k0]);
      #pragma unroll
      for (int mt = 0; mt < 4; ++mt)
        #pragma unroll
        for (int nt = 0; nt < 4; ++nt)
          acc[mt][nt] = __builtin_amdgcn_mfma_f32_16x16x32_bf16(a[mt], b[nt], acc[mt][nt], 0, 0, 0);
    }
    barrier_lds();  // all GEMM1 LDS reads done

    // Epilogue: lane holds 4 consecutive o (rows) at col pix -> b64 LDS write
    #pragma unroll
    for (int mt = 0; mt < 4; ++mt) {
      const int ob = wv * 64 + mt * 16 + quad * 4;
      const float4 bb = *(const float4*)(b1 + ob);
      #pragma unroll
      for (int nt = 0; nt < 4; ++nt) {
        const int pix = nt * 16 + r;
        ushort4 v;
        v.x = f2bf(silu(acc[mt][nt][0] + bb.x));
        v.y = f2bf(silu(acc[mt][nt][1] + bb.y));
        v.z = f2bf(silu(acc[mt][nt][2] + bb.z));
        v.w = f2bf(silu(acc[mt][nt][3] + bb.w));
        *(ushort4*)(&lds[pix * SP + ob]) = v;
      }
    }
  }
  barrier_lds();  // feat visible

  // ---------------- Phase 3: GEMM2  D[c4][pix] = conv_out_w . feat -> lds[pix][c4] ----------------
  {
    f32x4 acc[4][4];
    #pragma unroll
    for (int mt = 0; mt < 4; ++mt)
      #pragma unroll
      for (int nt = 0; nt < 4; ++nt)
        acc[mt][nt] = (f32x4){0.0f, 0.0f, 0.0f, 0.0f};

    #pragma unroll
    for (int k0 = 0; k0 < 256; k0 += 32) {
      bf16x8 a[4], b[4];
      #pragma unroll
      for (int mt = 0; mt < 4; ++mt) {  // A: conv_out_w rows c4
        const int row = wv * 64 + mt * 16 + r;
        if constexpr (WBF16)
          a[mt] = *(const bf16x8*)((const unsigned short*)w2p + row * 256 + quad * 8 + k0);
        else
          a[mt] = ldw8((const float*)w2p + row * 256 + quad * 8 + k0);
      }
      #pragma unroll
      for (int nt = 0; nt < 4; ++nt)   // B: feat[pix][o]
        b[nt] = *(const bf16x8*)(&lds[(nt * 16 + r) * SP + quad * 8 + k0]);
      #pragma unroll
      for (int mt = 0; mt < 4; ++mt)
        #pragma unroll
        for (int nt = 0; nt < 4; ++nt)
          acc[mt][nt] = __builtin_amdgcn_mfma_f32_16x16x32_bf16(a[mt], b[nt], acc[mt][nt], 0, 0, 0);
    }
    barrier_lds();  // all GEMM2 LDS reads done

    #pragma unroll
    for (int mt = 0; mt < 4; ++mt) {
      const int cb = wv * 64 + mt * 16 + quad * 4;
      const float4 bb = *(const float4*)(b2 + cb);
      #pragma unroll
      for (int nt = 0; nt < 4; ++nt) {
        const int pix = nt * 16 + r;
        ushort4 v;
        v.x = f2bf(acc[mt][nt][0] + bb.x);
        v.y = f2bf(acc[mt][nt][1] + bb.y);
        v.z = f2bf(acc[mt][nt][2] + bb.z);
        v.w = f2bf(acc[mt][nt][3] + bb.w);
        *(ushort4*)(&lds[pix * SP + cb]) = v;
      }
    }
  }
  barrier_lds();  // y visible

  // ---------------- Phase 4: IDWT + float4 stores (2 pixels/thread, 16B/lane) ----------------
  {
    float* ob_ = out + ((size_t)n * 64 * 128 + (size_t)(2 * hh)) * 128 + 4 * u;
    u16x8 yq[2][4];
    #pragma unroll
    for (int p = 0; p < 2; ++p)
      #pragma unroll
      for (int q = 0; q < 4; ++q)
        yq[p][q] = *(const u16x8*)(&lds[(2 * u + p) * SP + q * 64 + g * 8]);
    #pragma unroll
    for (int i = 0; i < 8; ++i) {
      float4 e, o;  // output rows 2hh (even) and 2hh+1 (odd), cols 4u..4u+3
      #pragma unroll
      for (int p = 0; p < 2; ++p) {
        const float y1 = 0.5f * bf2f(yq[p][0][i]);
        const float y2 = 0.5f * bf2f(yq[p][1][i]);
        const float y3 = 0.5f * bf2f(yq[p][2][i]);
        const float y4 = 0.5f * bf2f(yq[p][3][i]);
        const float s14 = y1 + y4, s23 = y2 + y3;
        const float d14 = y1 - y4, d23 = y2 - y3;
        if (p == 0) { e.x = s14 - s23; e.y = d14 + d23; o.x = d14 - d23; o.y = s14 + s23; }
        else        { e.z = s14 - s23; e.w = d14 + d23; o.z = d14 - d23; o.w = s14 + s23; }
      }
      float* prow = ob_ + (size_t)(g * 8 + i) * (128 * 128);
      *(float4*)prow         = e;
      *(float4*)(prow + 128) = o;
    }
  }
}

template <bool WBF16>
__global__ __launch_bounds__(256, 2)
void wavelet_fused(const float* __restrict__ x,
                   const void* __restrict__ w1p,
                   const float* __restrict__ b1,
                   const void* __restrict__ w2p,
                   const float* __restrict__ b2,
                   float* __restrict__ out)
{
  // One buffer, three lives: x_dwt [pix][c4] -> feat [pix][o] -> y [pix][c4].
  __shared__ unsigned short lds[64 * SP];  // 33,792 B -> 4 blocks/CU

  const int t = threadIdx.x;
  const int u = t & 31;             // 4-col group (pixels 2u, 2u+1) for phases 1/4
  const int g = t >> 5;             // 8-channel group for phases 1/4

  // XCD-chunked swizzle (bijective, grid 1024 = 8 XCD x 128): XCD owns hh in
  // [8*xcd, 8*xcd+8) for all images -> contiguous 16 h-rows (8KB) per plane per XCD.
  const int xcd = blockIdx.x & 7;
  const int j   = blockIdx.x >> 3;        // 0..127
  const int n   = j & 15;                 // image 0..15
  const int hh  = (xcd << 3) | (j >> 4);  // DWT row

  float4 st[16];  // 64-VGPR staging for this row's x

  load_st(x, n, hh, u, g, st);
  dwt_write(st, lds, u, g);
  barrier_lds();                   // x_dwt visible

  process_row<WBF16>(lds, w1p, b1, w2p, b2, out, n, hh, t, u, g);
}

extern "C" void kernel_launch(void* const* d_in, const int* in_sizes, int n_in,
                              void* d_out, int out_size, void* d_ws, size_t ws_size,
                              hipStream_t stream) {
  (void)in_sizes; (void)n_in; (void)out_size;
  const float* x  = (const float*)d_in[0];
  const float* w1 = (const float*)d_in[1];
  const float* b1 = (const float*)d_in[2];
  const float* w2 = (const float*)d_in[3];
  const float* b2 = (const float*)d_in[4];
  float* o = (float*)d_out;

  if (ws_size >= 2u * 65536u * sizeof(unsigned short)) {
    unsigned short* wb = (unsigned short*)d_ws;
    cvt_w<<<dim3(64), dim3(256), 0, stream>>>(w1, w2, wb);
    wavelet_fused<true><<<dim3(1024), dim3(256), 0, stream>>>(
        x, wb, b1, wb + 65536, b2, o);
  } else {
    wavelet_fused<false><<<dim3(1024), dim3(256), 0, stream>>>(
        x, w1, b1, w2, b2, o);
  }
}

// Round 13
// 145.149 us; speedup vs baseline: 1.1517x; 1.0420x over previous
//
#include <hip/hip_runtime.h>
#include <hip/hip_bf16.h>

// WaveletBlock fused kernel (f32 in/out): DWT -> GEMM1(+bias,SiLU) -> GEMM2(+bias) -> IDWT
// R16 = R10 verbatim (session best: 57us/dispatch, 146.16us total), locked in after the
// R15 regression (61us). 13-variant conclusion: the kernel is pattern-limited memory-bound
// at ~1.85 TB/s -- 1KB contiguous spans per channel plane at 64KB stride bound both the
// x-read and out-write streams; occupancy (20-54%), barrier semantics, intra-wave
// pipelining, direct-to-LDS staging, and cross-block TLP are all measured neutral or
// negative. The only real levers found: 16B/lane float4 access + XCD-chunked swizzle
// (this kernel) and LDS-only barriers (kept). Larger granules require multi-row register
// staging, which provably exceeds the 128-VGPR / 2-blocks-per-CU envelope (R6/R11/R12).
//  - grid 512, 2 rows per block (bid -> images 0..7, bid+512 -> images 8..15).
//  - phase-1 loads float4 16B/lane (u=t&31, g=t>>5); phase-4 float4 stores.
//  - XCD-chunked swizzle: xcd=bid&7 owns hh in [8*xcd, 8*xcd+8) -> contiguous 8KB
//    spans per channel plane per XCD L2.
//  - LDS-only barriers (s_waitcnt lgkmcnt(0); s_barrier): no vmcnt drain at barriers;
//    output stores fly across phase boundaries.
// All math harness-verified (absmax 0.015625).

typedef __bf16 bf16x8 __attribute__((ext_vector_type(8)));
typedef float  f32x4  __attribute__((ext_vector_type(4)));
typedef unsigned short u16x8 __attribute__((ext_vector_type(8)));

#define SP 264  // LDS row stride in bf16 elems: 528 B == 4 mod 32 banks (dwords);
                // rows 16B-aligned for ds_read_b128. GEMM-phase accesses <=2-way;
                // phase-1/4 b128 accesses alias 8-way = the 8-cycle hardware minimum.

__device__ __forceinline__ void barrier_lds() {
  // LDS-visibility barrier WITHOUT vmcnt drain (unlike __syncthreads).
  asm volatile("s_waitcnt lgkmcnt(0)\n\ts_barrier" ::: "memory");
}

__device__ __forceinline__ unsigned short f2bf(float f) {
  __hip_bfloat16 h = __float2bfloat16(f);
  return __builtin_bit_cast(unsigned short, h);
}
__device__ __forceinline__ float bf2f(unsigned short s) {
  union { unsigned int i; float f; } v; v.i = ((unsigned int)s) << 16; return v.f;
}
__device__ __forceinline__ float silu(float f) {
  return f / (1.0f + __expf(-f));
}
// Load 8 consecutive f32 weights, convert to a bf16x8 MFMA fragment (fallback path).
__device__ __forceinline__ bf16x8 ldw8(const float* __restrict__ p) {
  const float4 a = *(const float4*)p;
  const float4 b = *(const float4*)(p + 4);
  bf16x8 r;
  r[0] = (__bf16)a.x; r[1] = (__bf16)a.y; r[2] = (__bf16)a.z; r[3] = (__bf16)a.w;
  r[4] = (__bf16)b.x; r[5] = (__bf16)b.y; r[6] = (__bf16)b.z; r[7] = (__bf16)b.w;
  return r;
}

// Prelude: f32 -> bf16 weight conversion into workspace (no permutation).
__global__ __launch_bounds__(256) void cvt_w(const float* __restrict__ w1,
                                             const float* __restrict__ w2,
                                             unsigned short* __restrict__ o) {
  const int i = (blockIdx.x * 256 + threadIdx.x) * 4;  // grid 64 x 256 covers 65536
  const float4 a = *(const float4*)(w1 + i);
  const float4 b = *(const float4*)(w2 + i);
  *(ushort4*)(o + i)         = make_ushort4(f2bf(a.x), f2bf(a.y), f2bf(a.z), f2bf(a.w));
  *(ushort4*)(o + 65536 + i) = make_ushort4(f2bf(b.x), f2bf(b.y), f2bf(b.z), f2bf(b.w));
}

// Phase-1a: issue one row's x loads as float4 (16B/lane): thread t (u=t&31, g=t>>5)
// loads cols 4u..4u+3 of rows 2hh/2hh+1 for channels g*8..g*8+7. 16x dwordx4 = 64 VGPRs.
__device__ __forceinline__ void load_st(const float* __restrict__ x, int n, int hh,
                                        int u, int g, float4 (&st)[16]) {
  const float* xb = x + ((size_t)n * 64 * 128 + (size_t)(2 * hh)) * 128 + 4 * u;
  #pragma unroll
  for (int i = 0; i < 8; ++i) {
    const float* p = xb + (size_t)(g * 8 + i) * (128 * 128);
    st[2 * i]     = *(const float4*)p;          // row 2hh,   cols 4u..4u+3
    st[2 * i + 1] = *(const float4*)(p + 128);  // row 2hh+1, cols 4u..4u+3
  }
}

// Phase-1b: Haar DWT of staged regs -> lds[pix][q*64+c] as bf16, pixels 2u and 2u+1.
// 8x ds_write_b128; lane addr stride 8 banks + half-wave +4 -> 8-way = 8-cycle minimum.
__device__ __forceinline__ void dwt_write(const float4 (&st)[16], unsigned short* lds,
                                          int u, int g) {
  u16x8 v[4][2];
  #pragma unroll
  for (int i = 0; i < 8; ++i) {
    const float4 r0 = st[2 * i];
    const float4 r1 = st[2 * i + 1];
    #pragma unroll
    for (int p = 0; p < 2; ++p) {
      const float x1 = p ? r0.z : r0.x;  // even row, even col
      const float x3 = p ? r0.w : r0.y;  // even row, odd col
      const float x2 = p ? r1.z : r1.x;  // odd row,  even col
      const float x4 = p ? r1.w : r1.y;  // odd row,  odd col
      v[0][p][i] = f2bf(0.5f * ((x1 + x2) + (x3 + x4)));
      v[1][p][i] = f2bf(0.5f * ((x3 + x4) - (x1 + x2)));
      v[2][p][i] = f2bf(0.5f * ((x2 + x4) - (x1 + x3)));
      v[3][p][i] = f2bf(0.5f * ((x1 + x4) - (x2 + x3)));
    }
  }
  #pragma unroll
  for (int p = 0; p < 2; ++p)
    #pragma unroll
    for (int q = 0; q < 4; ++q)
      *(u16x8*)(&lds[(2 * u + p) * SP + q * 64 + g * 8]) = v[q][p];
}

// Phases 2-4 for one row (GEMM math verbatim; phase-4 is the float4 mirror of phase-1).
template <bool WBF16>
__device__ __forceinline__ void process_row(unsigned short* lds,
                                            const void* __restrict__ w1p,
                                            const float* __restrict__ b1,
                                            const void* __restrict__ w2p,
                                            const float* __restrict__ b2,
                                            float* __restrict__ out, int n, int hh,
                                            int t, int u, int g) {
  const int wv   = t >> 6;        // wave id: o-slice / c4-slice of 64 rows
  const int r    = t & 15;        // MFMA row/col-in-tile
  const int quad = (t & 63) >> 4; // MFMA quad: k-offset (inputs) / row-offset (output)

  // ---------------- Phase 2: GEMM1  D[o][pix] = conv_w . x_dwt;  silu -> lds[pix][o] ----------------
  {
    f32x4 acc[4][4];
    #pragma unroll
    for (int mt = 0; mt < 4; ++mt)
      #pragma unroll
      for (int nt = 0; nt < 4; ++nt)
        acc[mt][nt] = (f32x4){0.0f, 0.0f, 0.0f, 0.0f};

    #pragma unroll
    for (int k0 = 0; k0 < 256; k0 += 32) {
      bf16x8 a[4], b[4];
      #pragma unroll
      for (int mt = 0; mt < 4; ++mt) {  // A: conv_w rows o (L2-resident)
        const int row = wv * 64 + mt * 16 + r;
        if constexpr (WBF16)
          a[mt] = *(const bf16x8*)((const unsigned short*)w1p + row * 256 + quad * 8 + k0);
        else
          a[mt] = ldw8((const float*)w1p + row * 256 + quad * 8 + k0);
      }
      #pragma unroll
      for (int nt = 0; nt < 4; ++nt)   // B: x_dwt[pix][k] (ds_read_b128)
        b[nt] = *(const bf16x8*)(&lds[(nt * 16 + r) * SP + quad * 8 + k0]);
      #pragma unroll
      for (int mt = 0; mt < 4; ++mt)
        #pragma unroll
        for (int nt = 0; nt < 4; ++nt)
          acc[mt][nt] = __builtin_amdgcn_mfma_f32_16x16x32_bf16(a[mt], b[nt], acc[mt][nt], 0, 0, 0);
    }
    barrier_lds();  // all GEMM1 LDS reads done (staged row-loads stay in flight)

    // Epilogue: lane holds 4 consecutive o (rows) at col pix -> b64 LDS write
    #pragma unroll
    for (int mt = 0; mt < 4; ++mt) {
      const int ob = wv * 64 + mt * 16 + quad * 4;
      const float4 bb = *(const float4*)(b1 + ob);
      #pragma unroll
      for (int nt = 0; nt < 4; ++nt) {
        const int pix = nt * 16 + r;
        ushort4 v;
        v.x = f2bf(silu(acc[mt][nt][0] + bb.x));
        v.y = f2bf(silu(acc[mt][nt][1] + bb.y));
        v.z = f2bf(silu(acc[mt][nt][2] + bb.z));
        v.w = f2bf(silu(acc[mt][nt][3] + bb.w));
        *(ushort4*)(&lds[pix * SP + ob]) = v;
      }
    }
  }
  barrier_lds();  // feat visible

  // ---------------- Phase 3: GEMM2  D[c4][pix] = conv_out_w . feat -> lds[pix][c4] ----------------
  {
    f32x4 acc[4][4];
    #pragma unroll
    for (int mt = 0; mt < 4; ++mt)
      #pragma unroll
      for (int nt = 0; nt < 4; ++nt)
        acc[mt][nt] = (f32x4){0.0f, 0.0f, 0.0f, 0.0f};

    #pragma unroll
    for (int k0 = 0; k0 < 256; k0 += 32) {
      bf16x8 a[4], b[4];
      #pragma unroll
      for (int mt = 0; mt < 4; ++mt) {  // A: conv_out_w rows c4
        const int row = wv * 64 + mt * 16 + r;
        if constexpr (WBF16)
          a[mt] = *(const bf16x8*)((const unsigned short*)w2p + row * 256 + quad * 8 + k0);
        else
          a[mt] = ldw8((const float*)w2p + row * 256 + quad * 8 + k0);
      }
      #pragma unroll
      for (int nt = 0; nt < 4; ++nt)   // B: feat[pix][o]
        b[nt] = *(const bf16x8*)(&lds[(nt * 16 + r) * SP + quad * 8 + k0]);
      #pragma unroll
      for (int mt = 0; mt < 4; ++mt)
        #pragma unroll
        for (int nt = 0; nt < 4; ++nt)
          acc[mt][nt] = __builtin_amdgcn_mfma_f32_16x16x32_bf16(a[mt], b[nt], acc[mt][nt], 0, 0, 0);
    }
    barrier_lds();  // all GEMM2 LDS reads done

    #pragma unroll
    for (int mt = 0; mt < 4; ++mt) {
      const int cb = wv * 64 + mt * 16 + quad * 4;
      const float4 bb = *(const float4*)(b2 + cb);
      #pragma unroll
      for (int nt = 0; nt < 4; ++nt) {
        const int pix = nt * 16 + r;
        ushort4 v;
        v.x = f2bf(acc[mt][nt][0] + bb.x);
        v.y = f2bf(acc[mt][nt][1] + bb.y);
        v.z = f2bf(acc[mt][nt][2] + bb.z);
        v.w = f2bf(acc[mt][nt][3] + bb.w);
        *(ushort4*)(&lds[pix * SP + cb]) = v;
      }
    }
  }
  barrier_lds();  // y visible

  // ---------------- Phase 4: IDWT + float4 stores (2 pixels/thread, 16B/lane) ----------------
  {
    float* ob_ = out + ((size_t)n * 64 * 128 + (size_t)(2 * hh)) * 128 + 4 * u;
    u16x8 yq[2][4];
    #pragma unroll
    for (int p = 0; p < 2; ++p)
      #pragma unroll
      for (int q = 0; q < 4; ++q)
        yq[p][q] = *(const u16x8*)(&lds[(2 * u + p) * SP + q * 64 + g * 8]);
    #pragma unroll
    for (int i = 0; i < 8; ++i) {
      float4 e, o;  // output rows 2hh (even) and 2hh+1 (odd), cols 4u..4u+3
      #pragma unroll
      for (int p = 0; p < 2; ++p) {
        const float y1 = 0.5f * bf2f(yq[p][0][i]);
        const float y2 = 0.5f * bf2f(yq[p][1][i]);
        const float y3 = 0.5f * bf2f(yq[p][2][i]);
        const float y4 = 0.5f * bf2f(yq[p][3][i]);
        const float s14 = y1 + y4, s23 = y2 + y3;
        const float d14 = y1 - y4, d23 = y2 - y3;
        if (p == 0) { e.x = s14 - s23; e.y = d14 + d23; o.x = d14 - d23; o.y = s14 + s23; }
        else        { e.z = s14 - s23; e.w = d14 + d23; o.z = d14 - d23; o.w = s14 + s23; }
      }
      float* prow = ob_ + (size_t)(g * 8 + i) * (128 * 128);
      *(float4*)prow         = e;
      *(float4*)(prow + 128) = o;
    }
  }
}

template <bool WBF16>
__global__ __launch_bounds__(256, 2)
void wavelet_fused(const float* __restrict__ x,
                   const void* __restrict__ w1p,
                   const float* __restrict__ b1,
                   const void* __restrict__ w2p,
                   const float* __restrict__ b2,
                   float* __restrict__ out)
{
  // One buffer, three lives per row: x_dwt [pix][c4] -> feat [pix][o] -> y [pix][c4].
  __shared__ unsigned short lds[64 * SP];  // 33,792 B

  const int t = threadIdx.x;
  const int u = t & 31;             // 4-col group (pixels 2u, 2u+1) for phases 1/4
  const int g = t >> 5;             // 8-channel group for phases 1/4

  // XCD-chunked swizzle (bijective, grid 512 = 8 x 64): xcd owns hh in [8*xcd, 8*xcd+8)
  // for all images -> contiguous 16 h-rows (8KB) per channel plane per XCD.
  const int xcd = blockIdx.x & 7;
  const int k   = blockIdx.x >> 3;        // 0..63
  const int n0  = k & 7;                  // images 0..7 (row 0)
  const int hh  = (xcd << 3) | (k >> 3);  // DWT row
  const int n1  = n0 + 8;                 // images 8..15 (row 1), same hh

  float4 st[16];  // 64-VGPR staging: row i+1's x in flight across row i's GEMMs

  // ---- row 0: load + DWT ----
  load_st(x, n0, hh, u, g, st);
  dwt_write(st, lds, u, g);
  barrier_lds();                   // B1: x_dwt(row0) visible

  // issue row 1's loads NOW; with LDS-only barriers they stay in flight across
  // row-0's GEMM phases (no vmcnt(0) drain at any barrier).
  load_st(x, n1, hh, u, g, st);

  process_row<WBF16>(lds, w1p, b1, w2p, b2, out, n0, hh, t, u, g);

  barrier_lds();                   // B6: phase-4 row-0 LDS reads done before overwrite
  dwt_write(st, lds, u, g);        // row-1 DWT into freed buffer
  barrier_lds();                   // B7: x_dwt(row1) visible

  process_row<WBF16>(lds, w1p, b1, w2p, b2, out, n1, hh, t, u, g);
}

extern "C" void kernel_launch(void* const* d_in, const int* in_sizes, int n_in,
                              void* d_out, int out_size, void* d_ws, size_t ws_size,
                              hipStream_t stream) {
  (void)in_sizes; (void)n_in; (void)out_size;
  const float* x  = (const float*)d_in[0];
  const float* w1 = (const float*)d_in[1];
  const float* b1 = (const float*)d_in[2];
  const float* w2 = (const float*)d_in[3];
  const float* b2 = (const float*)d_in[4];
  float* o = (float*)d_out;

  if (ws_size >= 2u * 65536u * sizeof(unsigned short)) {
    unsigned short* wb = (unsigned short*)d_ws;
    cvt_w<<<dim3(64), dim3(256), 0, stream>>>(w1, w2, wb);
    wavelet_fused<true><<<dim3(512), dim3(256), 0, stream>>>(
        x, wb, b1, wb + 65536, b2, o);
  } else {
    wavelet_fused<false><<<dim3(512), dim3(256), 0, stream>>>(
        x, w1, b1, w2, b2, o);
  }
}